// Round 1
// baseline (410.879 us; speedup 1.0000x reference)
//
#include <hip/hip_runtime.h>
#include <math.h>

#define BB 64
#define LL 256
#define DD 1024

// ---------- row squared-norm: one block (256 thr) per row ----------
__global__ __launch_bounds__(256) void sqnorm_kernel(const float* __restrict__ x,
                                                     float* __restrict__ out) {
    int row = blockIdx.x;                       // 0 .. BB*LL-1
    const float* p = x + (size_t)row * DD;
    int t = threadIdx.x;
    float4 v = ((const float4*)p)[t];           // 256 * 4 = 1024 elements
    float s = v.x * v.x + v.y * v.y + v.z * v.z + v.w * v.w;
    #pragma unroll
    for (int off = 32; off; off >>= 1) s += __shfl_down(s, off, 64);
    __shared__ float red[4];
    if ((t & 63) == 0) red[t >> 6] = s;
    __syncthreads();
    if (t == 0) out[row] = red[0] + red[1] + red[2] + red[3];
}

// ---------- batched pairwise L2 distance (fp32 tiled GEMM) ----------
// tile 64x64 per block, K-chunk 16, 4x4 accumulators per thread
__global__ __launch_bounds__(256) void dist_kernel(const float* __restrict__ S,
                                                   const float* __restrict__ T,
                                                   const float* __restrict__ s2,
                                                   const float* __restrict__ t2,
                                                   float* __restrict__ dist) {
    int b  = blockIdx.z;
    int i0 = blockIdx.y * 64;
    int j0 = blockIdx.x * 64;
    const float* Sb = S + (size_t)b * LL * DD;
    const float* Tb = T + (size_t)b * LL * DD;

    __shared__ float sA[16][65];
    __shared__ float sB[16][65];

    int tid = threadIdx.x;
    int tx = tid & 15;     // output col group
    int ty = tid >> 4;     // output row group
    int lk = tid & 15;     // load: k within chunk
    int lm = tid >> 4;     // load: base row

    float acc[4][4] = {};

    for (int k0 = 0; k0 < DD; k0 += 16) {
        #pragma unroll
        for (int r = 0; r < 4; ++r) {
            int m = lm + 16 * r;
            sA[lk][m] = Sb[(size_t)(i0 + m) * DD + k0 + lk];
            sB[lk][m] = Tb[(size_t)(j0 + m) * DD + k0 + lk];
        }
        __syncthreads();
        #pragma unroll
        for (int kk = 0; kk < 16; ++kk) {
            float a[4], bv[4];
            #pragma unroll
            for (int ii = 0; ii < 4; ++ii) a[ii] = sA[kk][ty * 4 + ii];
            #pragma unroll
            for (int jj = 0; jj < 4; ++jj) bv[jj] = sB[kk][tx * 4 + jj];
            #pragma unroll
            for (int ii = 0; ii < 4; ++ii)
                #pragma unroll
                for (int jj = 0; jj < 4; ++jj)
                    acc[ii][jj] += a[ii] * bv[jj];
        }
        __syncthreads();
    }

    #pragma unroll
    for (int ii = 0; ii < 4; ++ii) {
        int i = i0 + ty * 4 + ii;
        float si = s2[b * LL + i];
        float4 o;
        float* op = &o.x;
        #pragma unroll
        for (int jj = 0; jj < 4; ++jj) {
            int j = j0 + tx * 4 + jj;
            float sq = si + t2[b * LL + j] - 2.0f * acc[ii][jj];
            op[jj] = sqrtf(fmaxf(sq, 1e-12f));
        }
        *(float4*)(&dist[((size_t)b * LL + i) * LL + j0 + tx * 4]) = o;
    }
}

// ---------- soft-DTW wavefront DP: one block per batch ----------
__global__ __launch_bounds__(256) void sdtw_kernel(const float* __restrict__ dist,
                                                   float* __restrict__ res) {
    int b = blockIdx.x;
    const float* Db = dist + (size_t)b * LL * LL;
    __shared__ float buf[3][LL + 2];            // diagonals indexed by j in [0,256]
    float* Dm2 = buf[0];
    float* Dm1 = buf[1];
    float* Dc  = buf[2];
    int t = threadIdx.x;
    const float INF = INFINITY;

    if (t == 0) { Dm2[0] = 0.0f; Dm1[0] = INF; Dm1[1] = INF; }
    __syncthreads();

    float last = 0.0f;
    for (int d = 2; d <= 2 * LL; ++d) {
        int j = t + 1;                          // 1..256
        int i = d - j;
        if (i >= 1 && i <= LL) {
            float a = Dm2[j - 1];               // R(i-1, j-1)
            float u = Dm1[j];                   // R(i-1, j)
            float c = Dm1[j - 1];               // R(i,   j-1)
            float m = fminf(a, fminf(u, c));
            float s = expf(m - a) + expf(m - u) + expf(m - c);
            float r = Db[(size_t)(i - 1) * LL + (j - 1)] + m - logf(s);
            Dc[j] = r;
            if (d == 2 * LL) last = r;          // only thread 255 (j=256)
        }
        if (t == 0) {
            Dc[0] = INF;                        // R(i, 0) = inf
            if (d <= LL) Dc[d] = INF;           // R(0, d) = inf
        }
        __syncthreads();
        float* tmp = Dm2; Dm2 = Dm1; Dm1 = Dc; Dc = tmp;
    }
    if (t == 255) res[b] = last;
}

// ---------- final mean over batches ----------
__global__ void reduce_kernel(const float* __restrict__ res, float* __restrict__ out) {
    int t = threadIdx.x;                        // 64 threads
    float v = res[t];
    #pragma unroll
    for (int off = 32; off; off >>= 1) v += __shfl_down(v, off, 64);
    if (t == 0) out[0] = v * (1.0f / BB);
}

extern "C" void kernel_launch(void* const* d_in, const int* in_sizes, int n_in,
                              void* d_out, int out_size, void* d_ws, size_t ws_size,
                              hipStream_t stream) {
    const float* S = (const float*)d_in[0];
    const float* T = (const float*)d_in[1];
    float* ws   = (float*)d_ws;
    float* dist = ws;                                   // 64*256*256 = 4,194,304 floats (16 MB)
    float* s2   = ws + (size_t)BB * LL * LL;            // 16384 floats
    float* t2   = s2 + BB * LL;                         // 16384 floats
    float* res  = t2 + BB * LL;                         // 64 floats

    sqnorm_kernel<<<BB * LL, 256, 0, stream>>>(S, s2);
    sqnorm_kernel<<<BB * LL, 256, 0, stream>>>(T, t2);

    dim3 g(LL / 64, LL / 64, BB);
    dist_kernel<<<g, 256, 0, stream>>>(S, T, s2, t2, dist);

    sdtw_kernel<<<BB, 256, 0, stream>>>(dist, res);
    reduce_kernel<<<1, 64, 0, stream>>>(res, (float*)d_out);
}

// Round 2
// 345.438 us; speedup vs baseline: 1.1894x; 1.1894x over previous
//
#include <hip/hip_runtime.h>
#include <hip/hip_bf16.h>
#include <math.h>

#define BB 64
#define LL 256
#define DD 1024
#define NDIAG 511   // anti-diagonals of the 256x256 dist matrix

// ---------- row squared-norm: one block (256 thr) per row ----------
__global__ __launch_bounds__(256) void sqnorm_kernel(const float* __restrict__ x,
                                                     float* __restrict__ out) {
    int row = blockIdx.x;                       // 0 .. BB*LL-1
    const float* p = x + (size_t)row * DD;
    int t = threadIdx.x;
    float4 v = ((const float4*)p)[t];           // 256 * 4 = 1024 elements
    float s = v.x * v.x + v.y * v.y + v.z * v.z + v.w * v.w;
    #pragma unroll
    for (int off = 32; off; off >>= 1) s += __shfl_down(s, off, 64);
    __shared__ float red[4];
    if ((t & 63) == 0) red[t >> 6] = s;
    __syncthreads();
    if (t == 0) out[row] = red[0] + red[1] + red[2] + red[3];
}

// ---------- batched pairwise L2 distance (fp32 tiled GEMM) ----------
// tile 64x64 per block, K-chunk 16, 4x4 accumulators per thread.
// Epilogue writes bf16 in ANTI-DIAGONAL-major layout: [b][p+q][q], each diag padded to 256.
__global__ __launch_bounds__(256) void dist_kernel(const float* __restrict__ S,
                                                   const float* __restrict__ T,
                                                   const float* __restrict__ s2,
                                                   const float* __restrict__ t2,
                                                   __hip_bfloat16* __restrict__ Dd) {
    int b  = blockIdx.z;
    int i0 = blockIdx.y * 64;
    int j0 = blockIdx.x * 64;
    const float* Sb = S + (size_t)b * LL * DD;
    const float* Tb = T + (size_t)b * LL * DD;

    __shared__ float sA[16][65];
    __shared__ float sB[16][65];

    int tid = threadIdx.x;
    int tx = tid & 15;     // output col group
    int ty = tid >> 4;     // output row group
    int lk = tid & 15;     // load: k within chunk
    int lm = tid >> 4;     // load: base row

    float acc[4][4] = {};

    for (int k0 = 0; k0 < DD; k0 += 16) {
        #pragma unroll
        for (int r = 0; r < 4; ++r) {
            int m = lm + 16 * r;
            sA[lk][m] = Sb[(size_t)(i0 + m) * DD + k0 + lk];
            sB[lk][m] = Tb[(size_t)(j0 + m) * DD + k0 + lk];
        }
        __syncthreads();
        #pragma unroll
        for (int kk = 0; kk < 16; ++kk) {
            float a[4], bv[4];
            #pragma unroll
            for (int ii = 0; ii < 4; ++ii) a[ii] = sA[kk][ty * 4 + ii];
            #pragma unroll
            for (int jj = 0; jj < 4; ++jj) bv[jj] = sB[kk][tx * 4 + jj];
            #pragma unroll
            for (int ii = 0; ii < 4; ++ii)
                #pragma unroll
                for (int jj = 0; jj < 4; ++jj)
                    acc[ii][jj] += a[ii] * bv[jj];
        }
        __syncthreads();
    }

    #pragma unroll
    for (int ii = 0; ii < 4; ++ii) {
        int p = i0 + ty * 4 + ii;
        float si = s2[b * LL + p];
        #pragma unroll
        for (int jj = 0; jj < 4; ++jj) {
            int q = j0 + tx * 4 + jj;
            float sq = si + t2[b * LL + q] - 2.0f * acc[ii][jj];
            float dv = sqrtf(fmaxf(sq, 1e-12f));
            Dd[((size_t)b * NDIAG + (p + q)) * 256 + q] = __float2bfloat16(dv);
        }
    }
}

// ---------- soft-DTW wavefront DP: ONE WAVE64 per batch, all-register ----------
// Lane L owns columns j = 4L+1 .. 4L+4 of the (257x257) R matrix.
// Cross-lane dep (col j-1 at lane boundary) handled by 2 shuffles per diagonal.
__device__ __forceinline__ float bf2f(unsigned short u) {
    return __uint_as_float(((unsigned)u) << 16);
}

__device__ __forceinline__ float sdtw_cell(int i, float dval, float diag2, float up1, float left1) {
    float m = fminf(diag2, fminf(up1, left1));
    float s = __expf(m - diag2) + __expf(m - up1) + __expf(m - left1);
    float r = dval + m - __logf(s);
    return (i >= 1 && i <= LL) ? r : INFINITY;
}

__global__ __launch_bounds__(64) void sdtw_kernel(const __hip_bfloat16* __restrict__ Dg,
                                                  float* __restrict__ res) {
    const int b = blockIdx.x;
    const int lane = threadIdx.x;               // 0..63
    const float INF = INFINITY;

    // diag storage: [b][dd][q], dd=p+q in 0..510, q padded to 256. Lane reads q = 4L..4L+3.
    const ushort4* base =
        (const ushort4*)((const unsigned short*)Dg + ((size_t)b * NDIAG) * 256 + 4 * lane);
    auto ld = [&](int dd) -> ushort4 {
        dd = dd > NDIAG - 1 ? NDIAG - 1 : dd;
        return base[(size_t)dd * 64];           // 256 ushorts per diag = 64 ushort4
    };

    // rm1 = R on diag d-1, rm2 = R on diag d-2, at this lane's columns.
    // init for d=2: diag1 cols>=1 are R[0][j]=inf (and unreal rows, never read);
    //               diag0 cols>=1 inf; col 0 handled via lane-0 override below.
    float rm1_0 = INF, rm1_1 = INF, rm1_2 = INF, rm1_3 = INF;
    float rm2_0 = INF, rm2_1 = INF, rm2_2 = INF, rm2_3 = INF;

    ushort4 pfA = ld(0), pfB = ld(1), pfC = ld(2), pfD = ld(3);

    const int jb = 4 * lane + 1;                // first column owned by this lane

#define SDTW_STEP(dcur, pkt)                                                   \
    {                                                                          \
        float p1 = __shfl_up(rm1_3, 1);  /* diag d-1, col 4L */                \
        float p2 = __shfl_up(rm2_3, 1);  /* diag d-2, col 4L */                \
        if (lane == 0) { p1 = INF; p2 = ((dcur) == 2) ? 0.0f : INF; }          \
        float d0 = bf2f(pkt.x), d1 = bf2f(pkt.y);                              \
        float d2v = bf2f(pkt.z), d3 = bf2f(pkt.w);                             \
        float rc0 = sdtw_cell((dcur) - (jb + 0), d0, p2,    rm1_0, p1);        \
        float rc1 = sdtw_cell((dcur) - (jb + 1), d1, rm2_0, rm1_1, rm1_0);     \
        float rc2 = sdtw_cell((dcur) - (jb + 2), d2v, rm2_1, rm1_2, rm1_1);    \
        float rc3 = sdtw_cell((dcur) - (jb + 3), d3, rm2_2, rm1_3, rm1_2);     \
        rm2_0 = rm1_0; rm2_1 = rm1_1; rm2_2 = rm1_2; rm2_3 = rm1_3;            \
        rm1_0 = rc0; rm1_1 = rc1; rm1_2 = rc2; rm1_3 = rc3;                    \
    }

    for (int d = 2; d <= 511; d += 2) {         // pairs (d, d+1): covers diags 2..511
        ushort4 cA = pfA, cB = pfB;
        pfA = pfC; pfB = pfD;
        pfC = ld(d + 2);
        pfD = ld(d + 3);
        SDTW_STEP(d, cA);
        SDTW_STEP(d + 1, cB);
    }
    SDTW_STEP(512, pfA);                        // final diagonal, dist dd=510

    if (lane == 63) res[b] = rm1_3;             // R[256][256]
#undef SDTW_STEP
}

// ---------- final mean over batches ----------
__global__ void reduce_kernel(const float* __restrict__ res, float* __restrict__ out) {
    int t = threadIdx.x;                        // 64 threads
    float v = res[t];
    #pragma unroll
    for (int off = 32; off; off >>= 1) v += __shfl_down(v, off, 64);
    if (t == 0) out[0] = v * (1.0f / BB);
}

extern "C" void kernel_launch(void* const* d_in, const int* in_sizes, int n_in,
                              void* d_out, int out_size, void* d_ws, size_t ws_size,
                              hipStream_t stream) {
    const float* S = (const float*)d_in[0];
    const float* T = (const float*)d_in[1];

    __hip_bfloat16* diag = (__hip_bfloat16*)d_ws;                 // 64*511*256*2 = 16,744,448 B
    char* ws8 = (char*)d_ws + (size_t)BB * NDIAG * 256 * 2;
    float* s2  = (float*)ws8;                                     // 16384 floats
    float* t2  = s2 + BB * LL;                                    // 16384 floats
    float* res = t2 + BB * LL;                                    // 64 floats

    sqnorm_kernel<<<BB * LL, 256, 0, stream>>>(S, s2);
    sqnorm_kernel<<<BB * LL, 256, 0, stream>>>(T, t2);

    dim3 g(LL / 64, LL / 64, BB);
    dist_kernel<<<g, 256, 0, stream>>>(S, T, s2, t2, diag);

    sdtw_kernel<<<BB, 64, 0, stream>>>(diag, res);
    reduce_kernel<<<1, 64, 0, stream>>>(res, (float*)d_out);
}

// Round 3
// 209.590 us; speedup vs baseline: 1.9604x; 1.6482x over previous
//
#include <hip/hip_runtime.h>
#include <math.h>

#define BB 64
#define LL 256
#define DD 1024
#define NDIAG 511   // anti-diagonals of the 256x256 dist matrix
#define BK 32

typedef __attribute__((ext_vector_type(8))) short short8v;
typedef __attribute__((ext_vector_type(4))) float float4v;

__device__ __forceinline__ unsigned short f2bf(float f) {
    unsigned u = __float_as_uint(f);
    unsigned r = (u + 0x7fffu + ((u >> 16) & 1u)) >> 16;   // RNE
    return (unsigned short)r;
}
__device__ __forceinline__ float bf2f(unsigned short u) {
    return __uint_as_float(((unsigned)u) << 16);
}

// ---------- prep: squared norms + fp32->bf16 copies (one block per row) ----------
__global__ __launch_bounds__(256) void prep_kernel(const float* __restrict__ S,
                                                   const float* __restrict__ T,
                                                   unsigned short* __restrict__ S16,
                                                   unsigned short* __restrict__ T16,
                                                   float* __restrict__ s2,
                                                   float* __restrict__ t2) {
    int rid = blockIdx.x;
    int t = threadIdx.x;
    const float* src;
    unsigned short* dst;
    float* nrm;
    if (rid < BB * LL) {
        src = S + (size_t)rid * DD; dst = S16 + (size_t)rid * DD; nrm = s2 + rid;
    } else {
        int r2 = rid - BB * LL;
        src = T + (size_t)r2 * DD; dst = T16 + (size_t)r2 * DD; nrm = t2 + r2;
    }
    float4 v = ((const float4*)src)[t];
    float s = v.x * v.x + v.y * v.y + v.z * v.z + v.w * v.w;
    ushort4 h;
    h.x = f2bf(v.x); h.y = f2bf(v.y); h.z = f2bf(v.z); h.w = f2bf(v.w);
    ((ushort4*)dst)[t] = h;
    #pragma unroll
    for (int off = 32; off; off >>= 1) s += __shfl_down(s, off, 64);
    __shared__ float red[4];
    if ((t & 63) == 0) red[t >> 6] = s;
    __syncthreads();
    if (t == 0) *nrm = red[0] + red[1] + red[2] + red[3];
}

// ---------- sqnorm only (fallback path) ----------
__global__ __launch_bounds__(256) void sqnorm_kernel(const float* __restrict__ x,
                                                     float* __restrict__ out) {
    int row = blockIdx.x;
    const float* p = x + (size_t)row * DD;
    int t = threadIdx.x;
    float4 v = ((const float4*)p)[t];
    float s = v.x * v.x + v.y * v.y + v.z * v.z + v.w * v.w;
    #pragma unroll
    for (int off = 32; off; off >>= 1) s += __shfl_down(s, off, 64);
    __shared__ float red[4];
    if ((t & 63) == 0) red[t >> 6] = s;
    __syncthreads();
    if (t == 0) out[row] = red[0] + red[1] + red[2] + red[3];
}

// ---------- MFMA bf16 distance GEMM: 128x128 tile, BK=32, 4 waves ----------
__global__ __launch_bounds__(256) void distmf_kernel(const unsigned short* __restrict__ S16,
                                                     const unsigned short* __restrict__ T16,
                                                     const float* __restrict__ s2,
                                                     const float* __restrict__ t2,
                                                     unsigned short* __restrict__ Dd) {
    __shared__ unsigned short lds[2][2][128 * BK];   // [buf][A/B][row*32+k], 32 KB
    const int b    = blockIdx.y;
    const int tile = blockIdx.x;
    const int i0 = (tile & 1) * 128;
    const int j0 = (tile >> 1) * 128;
    const int tid = threadIdx.x, w = tid >> 6, lane = tid & 63;
    const int wr = w >> 1, wc = w & 1;

    const unsigned short* Sg = S16 + ((size_t)b * LL + i0) * DD;
    const unsigned short* Tg = T16 + ((size_t)b * LL + j0) * DD;

    const int sr   = w * 16 + (lane >> 2);   // staging row within 64-row half
    const int skb0 = lane & 3;               // lds k-block slot this lane fills

    float4v acc[4][4];
    const float4v fzero = {0.f, 0.f, 0.f, 0.f};
    #pragma unroll
    for (int mi = 0; mi < 4; ++mi)
        #pragma unroll
        for (int ni = 0; ni < 4; ++ni) acc[mi][ni] = fzero;

    auto stage = [&](int buf, int k0) {
        #pragma unroll
        for (int n = 0; n < 2; ++n) {
            int r  = n * 64 + sr;
            int kb = skb0 ^ (r & 3);          // pre-swizzled GLOBAL source (LDS stays linear)
            __builtin_amdgcn_global_load_lds(
                (const __attribute__((address_space(1))) void*)(Sg + (size_t)r * DD + k0 + kb * 8),
                (__attribute__((address_space(3))) void*)(&lds[buf][0][(n * 64 + w * 16) * BK]),
                16, 0, 0);
            __builtin_amdgcn_global_load_lds(
                (const __attribute__((address_space(1))) void*)(Tg + (size_t)r * DD + k0 + kb * 8),
                (__attribute__((address_space(3))) void*)(&lds[buf][1][(n * 64 + w * 16) * BK]),
                16, 0, 0);
        }
    };

    stage(0, 0);
    for (int kt = 0; kt < 32; ++kt) {
        int cur = kt & 1;
        __syncthreads();                       // buf[cur] staged (vm drained), prev reads done
        if (kt < 31) stage(cur ^ 1, (kt + 1) * BK);

        const unsigned short* LA = &lds[cur][0][0];
        const unsigned short* LB = &lds[cur][1][0];
        short8v af[4], bf[4];
        #pragma unroll
        for (int mi = 0; mi < 4; ++mi) {
            int row = wr * 64 + mi * 16 + (lane & 15);
            int kb  = (lane >> 4) ^ (row & 3);
            af[mi] = *(const short8v*)(LA + row * BK + kb * 8);
        }
        #pragma unroll
        for (int ni = 0; ni < 4; ++ni) {
            int row = wc * 64 + ni * 16 + (lane & 15);
            int kb  = (lane >> 4) ^ (row & 3);
            bf[ni] = *(const short8v*)(LB + row * BK + kb * 8);
        }
        #pragma unroll
        for (int mi = 0; mi < 4; ++mi)
            #pragma unroll
            for (int ni = 0; ni < 4; ++ni)
                acc[mi][ni] = __builtin_amdgcn_mfma_f32_16x16x32_bf16(af[mi], bf[ni],
                                                                      acc[mi][ni], 0, 0, 0);
    }

    // epilogue: sq = s2+t2-2*dot -> sqrt -> bf16 store in diag-major layout
    const int r0 = (lane >> 4) * 4;
    const int cf = lane & 15;
    unsigned short* Db = Dd + (size_t)b * NDIAG * 256;
    #pragma unroll
    for (int mi = 0; mi < 4; ++mi) {
        #pragma unroll
        for (int ni = 0; ni < 4; ++ni) {
            int j = j0 + wc * 64 + ni * 16 + cf;
            float tj = t2[b * LL + j];
            #pragma unroll
            for (int rg = 0; rg < 4; ++rg) {
                int i = i0 + wr * 64 + mi * 16 + r0 + rg;
                float sq = s2[b * LL + i] + tj - 2.0f * acc[mi][ni][rg];
                float dv = sqrtf(fmaxf(sq, 1e-12f));
                Db[(size_t)(i + j) * 256 + j] = f2bf(dv);
            }
        }
    }
}

// ---------- fp32 tiled distance GEMM (fallback if ws too small) ----------
__global__ __launch_bounds__(256) void dist_kernel(const float* __restrict__ S,
                                                   const float* __restrict__ T,
                                                   const float* __restrict__ s2,
                                                   const float* __restrict__ t2,
                                                   unsigned short* __restrict__ Dd) {
    int b  = blockIdx.z;
    int i0 = blockIdx.y * 64;
    int j0 = blockIdx.x * 64;
    const float* Sb = S + (size_t)b * LL * DD;
    const float* Tb = T + (size_t)b * LL * DD;
    __shared__ float sA[16][65];
    __shared__ float sB[16][65];
    int tid = threadIdx.x;
    int tx = tid & 15, ty = tid >> 4, lk = tid & 15, lm = tid >> 4;
    float acc[4][4] = {};
    for (int k0 = 0; k0 < DD; k0 += 16) {
        #pragma unroll
        for (int r = 0; r < 4; ++r) {
            int m = lm + 16 * r;
            sA[lk][m] = Sb[(size_t)(i0 + m) * DD + k0 + lk];
            sB[lk][m] = Tb[(size_t)(j0 + m) * DD + k0 + lk];
        }
        __syncthreads();
        #pragma unroll
        for (int kk = 0; kk < 16; ++kk) {
            float a[4], bv[4];
            #pragma unroll
            for (int ii = 0; ii < 4; ++ii) a[ii] = sA[kk][ty * 4 + ii];
            #pragma unroll
            for (int jj = 0; jj < 4; ++jj) bv[jj] = sB[kk][tx * 4 + jj];
            #pragma unroll
            for (int ii = 0; ii < 4; ++ii)
                #pragma unroll
                for (int jj = 0; jj < 4; ++jj)
                    acc[ii][jj] += a[ii] * bv[jj];
        }
        __syncthreads();
    }
    #pragma unroll
    for (int ii = 0; ii < 4; ++ii) {
        int p = i0 + ty * 4 + ii;
        float si = s2[b * LL + p];
        #pragma unroll
        for (int jj = 0; jj < 4; ++jj) {
            int q = j0 + tx * 4 + jj;
            float sq = si + t2[b * LL + q] - 2.0f * acc[ii][jj];
            float dv = sqrtf(fmaxf(sq, 1e-12f));
            Dd[((size_t)b * NDIAG + (p + q)) * 256 + q] = f2bf(dv);
        }
    }
}

// ---------- soft-DTW wavefront DP: one wave64 per batch, all-register ----------
__device__ __forceinline__ float sdtw_cell(int i, float dval, float diag2, float up1, float left1) {
    float m = fminf(diag2, fminf(up1, left1));
    float s = __expf(m - diag2) + __expf(m - up1) + __expf(m - left1);
    float r = dval + m - __logf(s);
    return (i >= 1 && i <= LL) ? r : INFINITY;
}

__global__ __launch_bounds__(64) void sdtw_kernel(const unsigned short* __restrict__ Dg,
                                                  float* __restrict__ res) {
    const int b = blockIdx.x;
    const int lane = threadIdx.x;
    const float INF = INFINITY;

    const ushort4* base = (const ushort4*)(Dg + ((size_t)b * NDIAG) * 256 + 4 * lane);
    auto ld = [&](int dd) -> ushort4 {
        dd = dd > NDIAG - 1 ? NDIAG - 1 : dd;
        return base[(size_t)dd * 64];
    };

    float rm1_0 = INF, rm1_1 = INF, rm1_2 = INF, rm1_3 = INF;
    float rm2_0 = INF, rm2_1 = INF, rm2_2 = INF, rm2_3 = INF;
    const int jb = 4 * lane + 1;

#define SDTW_STEP(dcur, pkt)                                                   \
    {                                                                          \
        float p1 = __shfl_up(rm1_3, 1);                                        \
        float p2 = __shfl_up(rm2_3, 1);                                        \
        if (lane == 0) { p1 = INF; p2 = ((dcur) == 2) ? 0.0f : INF; }          \
        float d0 = bf2f(pkt.x), d1 = bf2f(pkt.y);                              \
        float d2v = bf2f(pkt.z), d3 = bf2f(pkt.w);                             \
        float rc0 = sdtw_cell((dcur) - (jb + 0), d0, p2,    rm1_0, p1);        \
        float rc1 = sdtw_cell((dcur) - (jb + 1), d1, rm2_0, rm1_1, rm1_0);     \
        float rc2 = sdtw_cell((dcur) - (jb + 2), d2v, rm2_1, rm1_2, rm1_1);    \
        float rc3 = sdtw_cell((dcur) - (jb + 3), d3, rm2_2, rm1_3, rm1_2);     \
        rm2_0 = rm1_0; rm2_1 = rm1_1; rm2_2 = rm1_2; rm2_3 = rm1_3;            \
        rm1_0 = rc0; rm1_1 = rc1; rm1_2 = rc2; rm1_3 = rc3;                    \
    }
#define LDCH(DST, C)                                                           \
    {                                                                          \
        _Pragma("unroll")                                                      \
        for (int q = 0; q < 16; ++q) DST[q] = ld(16 * (C) + q);                \
    }

    ushort4 A[16], Bv[16];
    LDCH(A, 0);
    LDCH(Bv, 1);

    // 512 steps d=2..513 (d=513 is a dummy; all its cells land out of range).
    for (int c = 0; c < 32; c += 2) {
        #pragma unroll
        for (int q = 0; q < 16; ++q) SDTW_STEP(16 * c + q + 2, A[q]);
        if (c + 2 < 32) LDCH(A, c + 2);
        #pragma unroll
        for (int q = 0; q < 16; ++q) SDTW_STEP(16 * (c + 1) + q + 2, Bv[q]);
        if (c + 3 < 32) LDCH(Bv, c + 3);
    }
    // after dummy step d=513: rm2 holds diag 512; lane 63 slot 3 = R[256][256]
    if (lane == 63) res[b] = rm2_3;
#undef SDTW_STEP
#undef LDCH
}

// ---------- final mean over batches ----------
__global__ void reduce_kernel(const float* __restrict__ res, float* __restrict__ out) {
    int t = threadIdx.x;
    float v = res[t];
    #pragma unroll
    for (int off = 32; off; off >>= 1) v += __shfl_down(v, off, 64);
    if (t == 0) out[0] = v * (1.0f / BB);
}

extern "C" void kernel_launch(void* const* d_in, const int* in_sizes, int n_in,
                              void* d_out, int out_size, void* d_ws, size_t ws_size,
                              hipStream_t stream) {
    const float* S = (const float*)d_in[0];
    const float* T = (const float*)d_in[1];

    const size_t nElem  = (size_t)BB * LL * DD;                 // 16,777,216
    const size_t nDiag  = (size_t)BB * NDIAG * 256;             // 8,372,224 ushorts
    const size_t needBF = nElem * 2 * sizeof(unsigned short)    // S16 + T16
                        + nDiag * sizeof(unsigned short)
                        + ((size_t)2 * BB * LL + BB) * sizeof(float);

    if (ws_size >= needBF) {
        unsigned short* S16  = (unsigned short*)d_ws;
        unsigned short* T16  = S16 + nElem;
        unsigned short* diag = T16 + nElem;
        float* s2  = (float*)(diag + nDiag);
        float* t2  = s2 + BB * LL;
        float* rsv = t2 + BB * LL;

        prep_kernel<<<2 * BB * LL, 256, 0, stream>>>(S, T, S16, T16, s2, t2);
        distmf_kernel<<<dim3(4, BB), 256, 0, stream>>>(S16, T16, s2, t2, diag);
        sdtw_kernel<<<BB, 64, 0, stream>>>(diag, rsv);
        reduce_kernel<<<1, 64, 0, stream>>>(rsv, (float*)d_out);
    } else {
        unsigned short* diag = (unsigned short*)d_ws;
        float* s2  = (float*)(diag + nDiag);
        float* t2  = s2 + BB * LL;
        float* rsv = t2 + BB * LL;

        sqnorm_kernel<<<BB * LL, 256, 0, stream>>>(S, s2);
        sqnorm_kernel<<<BB * LL, 256, 0, stream>>>(T, t2);
        dim3 g(LL / 64, LL / 64, BB);
        dist_kernel<<<g, 256, 0, stream>>>(S, T, s2, t2, diag);
        sdtw_kernel<<<BB, 64, 0, stream>>>(diag, rsv);
        reduce_kernel<<<1, 64, 0, stream>>>(rsv, (float*)d_out);
    }
}